// Round 19
// baseline (387.150 us; speedup 1.0000x reference)
//
#include <hip/hip_runtime.h>
#include <math.h>

#define EM_EPS 1e-8f
#define BN_SC 0.999995000037f   // 1/sqrt(1+1e-5)
#define LOG2PI 1.8378770664093453f

// ---------------- conv1 (5x5 s2 VALID) + bn1 ----------------
__global__ __launch_bounds__(256) void k_conv1(
    const float* __restrict__ x, const float* __restrict__ w,
    const float* __restrict__ g, const float* __restrict__ bb,
    float* __restrict__ out) {
  int idx = blockIdx.x * 256 + threadIdx.x;
  int ox = idx % 14; int t = idx / 14;
  int oy = t % 14; t /= 14;
  int co = t % 256; int b = t / 256;
  const float* xb = x + b * 3 * 1024;
  const float* wc = w + co * 75;
  float acc = 0.f;
  #pragma unroll
  for (int ci = 0; ci < 3; ++ci) {
    const float* xc = xb + ci * 1024 + (oy * 2) * 32 + ox * 2;
    const float* wk = wc + ci * 25;
    #pragma unroll
    for (int kh = 0; kh < 5; ++kh)
      #pragma unroll
      for (int kw = 0; kw < 5; ++kw)
        acc = fmaf(xc[kh * 32 + kw], wk[kh * 5 + kw], acc);
  }
  out[idx] = acc * (g[co] * BN_SC) + bb[co];
}

// ------- conv2 POSE partial: 256 co = 4 clean groups of 64, 4 co/thread -------
// grid = 32 b x 4 groups x NKC kc; 192 thr = 12 rows x 16 cg.
// partial_p [kc][b][px144][256]
template<int NKC>
__global__ __launch_bounds__(192, 4) void k_conv2_part4p(
    const float* __restrict__ in,
    const float* __restrict__ wp,
    float* __restrict__ partial_p) {
  constexpr int NCI = 256 / NKC;
  __shared__ float s_in[8 * 14 * 16];    // [ci8][iy][ix pad16]
  __shared__ float s_w[72 * 68];         // [ci8*9+tap][co pad68]

  const int t   = threadIdx.x;
  const int row = t >> 4;
  const int cg  = t & 15;
  const int b   = blockIdx.x / (4 * NKC);
  const int r   = blockIdx.x % (4 * NKC);
  const int gco = (r / NKC) * 64;
  const int kc  = r % NKC;
  const float* inb = in + (size_t)b * 50176;

  float acc[4][12];
  #pragma unroll
  for (int u = 0; u < 4; ++u)
    #pragma unroll
    for (int px = 0; px < 12; ++px) acc[u][px] = 0.f;

  for (int cc = 0; cc < NCI / 8; ++cc) {
    const int ci0 = kc * NCI + cc * 8;
    __syncthreads();
    for (int idx = t; idx < 1568; idx += 192) {
      int ci = idx / 196, rr = idx - ci * 196;
      int iy = rr / 14, ix = rr - iy * 14;
      s_in[ci * 224 + iy * 16 + ix] = inb[(size_t)ci0 * 196 + idx];
    }
    for (int idx = t; idx < 4608; idx += 192) {
      int co = idx / 72, rem = idx - co * 72;
      s_w[rem * 68 + co] = wp[(size_t)(gco + co) * 2304 + ci0 * 9 + rem];
    }
    __syncthreads();

    for (int ci = 0; ci < 8; ++ci) {
      float rin[3][16];
      #pragma unroll
      for (int kh = 0; kh < 3; ++kh) {
        const float4* rp = (const float4*)&s_in[ci * 224 + (row + kh) * 16];
        #pragma unroll
        for (int x = 0; x < 4; ++x)
          *(float4*)&rin[kh][x * 4] = rp[x];
      }
      #pragma unroll
      for (int kh = 0; kh < 3; ++kh) {
        #pragma unroll
        for (int kw = 0; kw < 3; ++kw) {
          const float4 wq = *(const float4*)&s_w[(ci * 9 + kh * 3 + kw) * 68 + cg * 4];
          #pragma unroll
          for (int px = 0; px < 12; ++px) {
            float iv = rin[kh][px + kw];
            acc[0][px] = fmaf(iv, wq.x, acc[0][px]);
            acc[1][px] = fmaf(iv, wq.y, acc[1][px]);
            acc[2][px] = fmaf(iv, wq.z, acc[2][px]);
            acc[3][px] = fmaf(iv, wq.w, acc[3][px]);
          }
        }
      }
    }
  }

  const int c = gco + cg * 4;
  #pragma unroll
  for (int px = 0; px < 12; ++px) {
    float* dst = partial_p +
        (((size_t)(kc * 32 + b) * 144) + row * 12 + px) * 256 + c;
    *(float4*)dst = make_float4(acc[0][px], acc[1][px], acc[2][px], acc[3][px]);
  }
}

// ------- conv2 A partial: 16 co, 1 co/thread -------
// grid = 32 b x NKC kc; 192 thr = 12 rows x 16 co. partial_a [kc][b][px144][16]
template<int NKC>
__global__ __launch_bounds__(192, 4) void k_conv2_part4a(
    const float* __restrict__ in,
    const float* __restrict__ wa,
    float* __restrict__ partial_a) {
  constexpr int NCI = 256 / NKC;
  __shared__ float s_in[8 * 14 * 16];    // 7.2 KB
  __shared__ float s_wa[72 * 17];        // [ci8*9+tap][co pad17] 4.9 KB

  const int t   = threadIdx.x;
  const int row = t >> 4;
  const int cg  = t & 15;
  const int b   = blockIdx.x / NKC;
  const int kc  = blockIdx.x % NKC;
  const float* inb = in + (size_t)b * 50176;

  float acc[12];
  #pragma unroll
  for (int px = 0; px < 12; ++px) acc[px] = 0.f;

  for (int cc = 0; cc < NCI / 8; ++cc) {
    const int ci0 = kc * NCI + cc * 8;
    __syncthreads();
    for (int idx = t; idx < 1568; idx += 192) {
      int ci = idx / 196, rr = idx - ci * 196;
      int iy = rr / 14, ix = rr - iy * 14;
      s_in[ci * 224 + iy * 16 + ix] = inb[(size_t)ci0 * 196 + idx];
    }
    for (int idx = t; idx < 1152; idx += 192) {
      int co = idx / 72, rem = idx - co * 72;
      s_wa[rem * 17 + co] = wa[(size_t)co * 2304 + ci0 * 9 + rem];
    }
    __syncthreads();

    for (int ci = 0; ci < 8; ++ci) {
      float rin[3][16];
      #pragma unroll
      for (int kh = 0; kh < 3; ++kh) {
        const float4* rp = (const float4*)&s_in[ci * 224 + (row + kh) * 16];
        #pragma unroll
        for (int x = 0; x < 4; ++x)
          *(float4*)&rin[kh][x * 4] = rp[x];
      }
      #pragma unroll
      for (int kh = 0; kh < 3; ++kh) {
        #pragma unroll
        for (int kw = 0; kw < 3; ++kw) {
          const float wv = s_wa[(ci * 9 + kh * 3 + kw) * 17 + cg];
          #pragma unroll
          for (int px = 0; px < 12; ++px)
            acc[px] = fmaf(rin[kh][px + kw], wv, acc[px]);
        }
      }
    }
  }

  float* dst = partial_a +
      (((size_t)(kc * 32 + b) * 144) + row * 12) * 16 + cg;
  #pragma unroll
  for (int px = 0; px < 12; ++px) dst[px * 16] = acc[px];
}

// ------- conv2 reduce (vectorized): quad per thread, a + pose paths -------
template<int NKC>
__global__ __launch_bounds__(256) void k_conv2_red(
    const float* __restrict__ partial_p,
    const float* __restrict__ partial_a,
    const float* __restrict__ ga, const float* __restrict__ bba,
    const float* __restrict__ gp, const float* __restrict__ bbp,
    float* __restrict__ a1, float* __restrict__ pose1) {
  int q = blockIdx.x * 256 + threadIdx.x;
  if (q >= 32 * 144 * 68) return;
  int cq = q % 68; int r = q / 68;
  int px = r % 144; int b = r / 144;
  const int c4 = cq * 4;
  if (c4 < 16) {
    const size_t base = ((size_t)b * 144 + px) * 16 + c4;
    const size_t kstr = (size_t)32 * 144 * 16;
    float4 s = make_float4(0.f, 0.f, 0.f, 0.f);
    #pragma unroll
    for (int k = 0; k < NKC; ++k) {
      float4 v = *(const float4*)(partial_a + base + k * kstr);
      s.x += v.x; s.y += v.y; s.z += v.z; s.w += v.w;
    }
    float4 o;
    o.x = 1.f / (1.f + __expf(-(s.x * (ga[c4 + 0] * BN_SC) + bba[c4 + 0])));
    o.y = 1.f / (1.f + __expf(-(s.y * (ga[c4 + 1] * BN_SC) + bba[c4 + 1])));
    o.z = 1.f / (1.f + __expf(-(s.z * (ga[c4 + 2] * BN_SC) + bba[c4 + 2])));
    o.w = 1.f / (1.f + __expf(-(s.w * (ga[c4 + 3] * BN_SC) + bba[c4 + 3])));
    *(float4*)(a1 + ((size_t)b * 144 + px) * 16 + c4) = o;
  } else {
    const int cp = c4 - 16;
    const size_t base = ((size_t)b * 144 + px) * 256 + cp;
    const size_t kstr = (size_t)32 * 144 * 256;
    float4 s = make_float4(0.f, 0.f, 0.f, 0.f);
    #pragma unroll
    for (int k = 0; k < NKC; ++k) {
      float4 v = *(const float4*)(partial_p + base + k * kstr);
      s.x += v.x; s.y += v.y; s.z += v.z; s.w += v.w;
    }
    float4 o;
    o.x = s.x * (gp[cp + 0] * BN_SC) + bbp[cp + 0];
    o.y = s.y * (gp[cp + 1] * BN_SC) + bbp[cp + 1];
    o.z = s.z * (gp[cp + 2] * BN_SC) + bbp[cp + 2];
    o.w = s.w * (gp[cp + 3] * BN_SC) + bbp[cp + 3];
    *(float4*)(pose1 + ((size_t)b * 144 + px) * 256 + cp) = o;
  }
}

// ------------- conv2 single-pass fallback (ws too small); channel-last out ----
__global__ __launch_bounds__(192) void k_conv2(
    const float* __restrict__ in,
    const float* __restrict__ wa, const float* __restrict__ wp,
    const float* __restrict__ ga, const float* __restrict__ bba,
    const float* __restrict__ gp, const float* __restrict__ bbp,
    float* __restrict__ a1, float* __restrict__ pose1) {
  __shared__ float s_in[16 * 14 * 16];
  __shared__ float s_w[16 * 9 * 34];

  const int t   = threadIdx.x;
  const int row = t >> 4;
  const int cg  = t & 15;
  const int b   = blockIdx.x / 9;
  const int gco = (blockIdx.x % 9) * 32;
  const float* inb = in + b * 50176;

  float acc[2][12];
  #pragma unroll
  for (int u = 0; u < 2; ++u)
    #pragma unroll
    for (int px = 0; px < 12; ++px) acc[u][px] = 0.f;

  for (int ch = 0; ch < 16; ++ch) {
    __syncthreads();
    for (int idx = t; idx < 3136; idx += 192) {
      int ci = idx / 196, rr = idx - ci * 196;
      int iy = rr / 14, ix = rr - iy * 14;
      s_in[ci * 224 + iy * 16 + ix] = inb[ch * 3136 + idx];
    }
    for (int idx = t; idx < 4608; idx += 192) {
      int co = idx / 144, rem = idx - co * 144;
      int c = gco + co;
      float val = 0.f;
      if (c < 272) {
        const float* wrow = (c < 16) ? (wa + c * 2304) : (wp + (c - 16) * 2304);
        val = wrow[ch * 144 + rem];
      }
      s_w[rem * 34 + co] = val;
    }
    __syncthreads();

    for (int ci = 0; ci < 16; ++ci) {
      float rin[3][16];
      #pragma unroll
      for (int kh = 0; kh < 3; ++kh) {
        const float4* rp = (const float4*)&s_in[ci * 224 + (row + kh) * 16];
        #pragma unroll
        for (int x = 0; x < 4; ++x)
          *(float4*)&rin[kh][x * 4] = rp[x];
      }
      #pragma unroll
      for (int kh = 0; kh < 3; ++kh) {
        #pragma unroll
        for (int kw = 0; kw < 3; ++kw) {
          float2 wv = *(const float2*)&s_w[(ci * 9 + kh * 3 + kw) * 34 + cg * 2];
          #pragma unroll
          for (int px = 0; px < 12; ++px) {
            float iv = rin[kh][px + kw];
            acc[0][px] = fmaf(iv, wv.x, acc[0][px]);
            acc[1][px] = fmaf(iv, wv.y, acc[1][px]);
          }
        }
      }
    }
  }

  #pragma unroll
  for (int u = 0; u < 2; ++u) {
    int c = gco + cg * 2 + u;
    if (c >= 272) continue;
    if (c < 16) {
      float g_ = ga[c] * BN_SC, b_ = bba[c];
      #pragma unroll
      for (int px = 0; px < 12; ++px) {
        float v = acc[u][px] * g_ + b_;
        a1[((size_t)b * 144 + row * 12 + px) * 16 + c] = 1.f / (1.f + expf(-v));
      }
    } else {
      int cp = c - 16;
      float g_ = gp[cp] * BN_SC, b_ = bbp[cp];
      #pragma unroll
      for (int px = 0; px < 12; ++px)
        pose1[((size_t)b * 144 + row * 12 + px) * 256 + cp] = acc[u][px] * g_ + b_;
    }
  }
}

// ---------------- EM routing v9: channel-last I/O, 8 waves, 8 p's per lane ----
template<int K, int S, int P, int HIN, int WIN, int OH, int OW, int B>
__global__ __launch_bounds__(512, 1) void k_routing(
    const float* __restrict__ ag,
    const float* __restrict__ poseg,
    const float* __restrict__ Wg,      // (KKA,B,4,4)
    const float* __restrict__ bu, const float* __restrict__ ba,
    const float* __restrict__ bng, const float* __restrict__ bnb,
    float* __restrict__ aout_g,
    float* __restrict__ pose_out_g) {
  constexpr int KK = K * K;
  constexpr int KKA = KK * 16;
  constexpr int NW = 8;
  constexpr int KPW = KKA / NW;       // 18 or 32
  constexpr int NSTEP = KPW / 2;      // 9 or 16
  static_assert(KPW % 2 == 0, "KPW%2");

  __shared__ __attribute__((aligned(16))) float s_pp[KKA * 16];
  __shared__ float s_ain[KKA];
  __shared__ __attribute__((aligned(16))) float s_part[NW][2][16][20]; // U1[8]|U2[8]|RS
  __shared__ __attribute__((aligned(16))) float s_mu[16 * 20];   // [j][p] pad20
  __shared__ __attribute__((aligned(16))) float s_i2s[16 * 20];  // [j][p] pad20
  __shared__ float s_lt[16 * 16];    // [p][j] log(sigma2)
  __shared__ float s_rs[16];         // fRS per j
  __shared__ float s_Ej[16];

  const int t  = threadIdx.x;
  const int wv = t >> 6;
  const int ln = t & 63;
  const int j  = ln & 15;
  const int ph = (ln >> 4) & 1;
  const int kq = ln >> 5;
  const int jc = (j < B) ? j : 0;

  const int bi = blockIdx.x;
  const int b  = bi / (OH * OW);
  const int l  = bi % (OH * OW);
  const int oy = l / OW, ox = l % OW;

  // ---- coalesced staging: per tap, contiguous 256 (pose) / 16 (a) floats ----
  for (int idx = t; idx < KK * 256; idx += 512) {
    int kki = idx >> 8, c = idx & 255;
    int kh = kki / K, kw = kki % K;
    int iy = oy * S - P + kh, ix = ox * S - P + kw;
    float val = 0.f;
    if (iy >= 0 && iy < HIN && ix >= 0 && ix < WIN) {
      val = poseg[((size_t)((b * HIN + iy) * WIN + ix)) * 256 + c];
      if (bng) val = val * (bng[c] * BN_SC) + bnb[c];
    }
    s_pp[idx] = val;
  }
  for (int idx = t; idx < KK * 16; idx += 512) {
    int kki = idx >> 4, acap = idx & 15;
    int kh = kki / K, kw = kki % K;
    int iy = oy * S - P + kh, ix = ox * S - P + kw;
    float val = 0.f;
    if (iy >= 0 && iy < HIN && ix >= 0 && ix < WIN)
      val = ag[((size_t)((b * HIN + iy) * WIN + ix)) * 16 + acap];
    s_ain[idx] = val;
  }
  __syncthreads();

  const int kbase = wv * KPW + kq;
  const float* wjc = Wg + (size_t)jc * 16;

  float p95 = 0.95f;
  for (int it = 0; it < 3; ++it) {
    const float lam = 0.01f * (1.0f - p95);
    p95 *= 0.95f;
    float U1[8], U2[8], RS = 0.f;
    #pragma unroll
    for (int p = 0; p < 8; ++p) { U1[p] = 0.f; U2[p] = 0.f; }

    float mu[8], i2s[8], Ej = 0.f;
    if (it > 0) {
      const float4* mp = (const float4*)&s_mu[j * 20 + ph * 8];
      const float4* ip = (const float4*)&s_i2s[j * 20 + ph * 8];
      float4 m0 = mp[0], m1 = mp[1], i0 = ip[0], i1 = ip[1];
      mu[0] = m0.x; mu[1] = m0.y; mu[2] = m0.z; mu[3] = m0.w;
      mu[4] = m1.x; mu[5] = m1.y; mu[6] = m1.z; mu[7] = m1.w;
      i2s[0] = i0.x; i2s[1] = i0.y; i2s[2] = i0.z; i2s[3] = i0.w;
      i2s[4] = i1.x; i2s[5] = i1.y; i2s[6] = i1.z; i2s[7] = i1.w;
      Ej = s_Ej[j];
    }

    for (int st = 0; st < NSTEP; ++st) {
      const int k = kbase + st * 2;
      const float4* wrp = (const float4*)(wjc + (size_t)k * B * 16);
      const float4 cw0 = wrp[0], cw1 = wrp[1], cw2 = wrp[2], cw3 = wrp[3];
      const float4* pr = (const float4*)&s_pp[k * 16 + ph * 8];
      const float4 pA = pr[0], pB = pr[1];
      const float ain = s_ain[k];
      float vv[8];
      vv[0] = pA.x * cw0.x + pA.y * cw1.x + pA.z * cw2.x + pA.w * cw3.x;
      vv[1] = pA.x * cw0.y + pA.y * cw1.y + pA.z * cw2.y + pA.w * cw3.y;
      vv[2] = pA.x * cw0.z + pA.y * cw1.z + pA.z * cw2.z + pA.w * cw3.z;
      vv[3] = pA.x * cw0.w + pA.y * cw1.w + pA.z * cw2.w + pA.w * cw3.w;
      vv[4] = pB.x * cw0.x + pB.y * cw1.x + pB.z * cw2.x + pB.w * cw3.x;
      vv[5] = pB.x * cw0.y + pB.y * cw1.y + pB.z * cw2.y + pB.w * cw3.y;
      vv[6] = pB.x * cw0.z + pB.y * cw1.z + pB.z * cw2.z + pB.w * cw3.z;
      vv[7] = pB.x * cw0.w + pB.y * cw1.w + pB.z * cw2.w + pB.w * cw3.w;
      float ra;
      if (it == 0) {
        ra = ain * (1.0f / (float)B);
      } else {
        float sa = 0.f, sb = 0.f;
        #pragma unroll
        for (int z = 0; z < 4; ++z) {
          float d0 = vv[z] - mu[z];
          float d1 = vv[4 + z] - mu[4 + z];
          sa = fmaf(d0 * i2s[z], d0, sa);
          sb = fmaf(d1 * i2s[4 + z], d1, sb);
        }
        float ss = sa + sb;
        ss += __shfl_xor(ss, 16);
        float e = Ej * __expf(-ss);
        float sm = e + __shfl_xor(e, 1);
        sm += __shfl_xor(sm, 2);
        sm += __shfl_xor(sm, 4);
        sm += __shfl_xor(sm, 8);
        ra = e * __builtin_amdgcn_rcpf(sm + 1e-30f) * ain;
      }
      RS += ra;
      #pragma unroll
      for (int p = 0; p < 8; ++p) {
        float tv = ra * vv[p];
        U1[p] += tv;
        U2[p] = fmaf(tv, vv[p], U2[p]);
      }
    }

    #pragma unroll
    for (int p = 0; p < 8; ++p) {
      U1[p] += __shfl_xor(U1[p], 32);
      U2[p] += __shfl_xor(U2[p], 32);
    }
    RS += __shfl_xor(RS, 32);

    if (ln < 32) {
      float* dst = &s_part[wv][ph][j][0];
      ((float4*)dst)[0] = make_float4(U1[0], U1[1], U1[2], U1[3]);
      ((float4*)dst)[1] = make_float4(U1[4], U1[5], U1[6], U1[7]);
      ((float4*)dst)[2] = make_float4(U2[0], U2[1], U2[2], U2[3]);
      ((float4*)dst)[3] = make_float4(U2[4], U2[5], U2[6], U2[7]);
      dst[16] = RS;
    }
    __syncthreads();

    if (t < 256) {
      const int p2 = t >> 4;
      const int j2 = t & 15;
      const int ph2 = p2 >> 3, q = p2 & 7;
      float fU1 = 0.f, fU2 = 0.f, fRS = 0.f;
      #pragma unroll
      for (int w2 = 0; w2 < NW; ++w2) {
        fU1 += s_part[w2][ph2][j2][q];
        fU2 += s_part[w2][ph2][j2][8 + q];
        fRS += s_part[w2][ph2][j2][16];
      }
      const bool jv2 = (j2 < B);
      const float inv = 1.f / (fRS + EM_EPS);
      const float Cc  = fRS * inv;
      float muv = fU1 * inv;
      float s2 = fU2 * inv - muv * muv * (2.f - Cc);
      s2 = fmaxf(s2, 0.f) + EM_EPS;
      s_mu[j2 * 20 + p2]  = jv2 ? muv : 0.f;
      s_i2s[j2 * 20 + p2] = jv2 ? (0.5f * __builtin_amdgcn_rcpf(s2)) : 0.f;
      s_lt[p2 * 16 + j2]  = __logf(s2);
      if (p2 == 0) s_rs[j2] = fRS;
      if (it == 2 && jv2 && pose_out_g)
        pose_out_g[((size_t)((b * OH + oy) * OW + ox)) * 256 + j2 * 16 + p2] = muv;
    }
    __syncthreads();

    if (t < 16) {
      const int j2 = t;
      const bool jv2 = (j2 < B);
      float lsum = 0.f;
      #pragma unroll
      for (int p = 0; p < 16; ++p) lsum += s_lt[p * 16 + j2];
      const float fRS = s_rs[j2];
      const float cost = (16.f * bu[jv2 ? j2 : 0] + 0.5f * lsum) * fRS;
      const float aout = 1.f / (1.f + __expf(-(lam * (ba[jv2 ? j2 : 0] - cost))));
      if (it < 2) {
        const float L0 = -0.5f * (16.f * LOG2PI + lsum);
        const float lj = L0 + __logf(aout + EM_EPS);
        float mj = jv2 ? lj : -1e30f;
        mj = fmaxf(mj, __shfl_xor(mj, 1));
        mj = fmaxf(mj, __shfl_xor(mj, 2));
        mj = fmaxf(mj, __shfl_xor(mj, 4));
        mj = fmaxf(mj, __shfl_xor(mj, 8));
        s_Ej[j2] = jv2 ? __expf(lj - mj) : 0.f;
      } else if (jv2) {
        aout_g[((size_t)((b * OH + oy) * OW + ox)) * B + j2] = aout;
      }
    }
    if (it < 2) __syncthreads();
  }
}

// ---------------- spatial mean over a4 [b][25][10] ----------------
__global__ __launch_bounds__(64) void k_mean(const float* __restrict__ a4,
                                             float* __restrict__ out) {
  int idx = blockIdx.x * 64 + threadIdx.x;
  if (idx >= 320) return;
  int b = idx / 10, j = idx % 10;
  const float* pa = a4 + b * 250 + j;
  float s = 0.f;
  #pragma unroll
  for (int i = 0; i < 25; ++i) s += pa[i * 10];
  out[idx] = s * (1.f / 25.f);
}

extern "C" void kernel_launch(void* const* d_in, const int* in_sizes, int n_in,
                              void* d_out, int out_size, void* d_ws, size_t ws_size,
                              hipStream_t stream) {
  const float* x       = (const float*)d_in[0];
  const float* conv1_w = (const float*)d_in[1];
  const float* bn1_g   = (const float*)d_in[2];
  const float* bn1_b   = (const float*)d_in[3];
  const float* conva_w = (const float*)d_in[4];
  const float* bna_g   = (const float*)d_in[5];
  const float* bna_b   = (const float*)d_in[6];
  const float* convp_w = (const float*)d_in[7];
  const float* bnp_g   = (const float*)d_in[8];
  const float* bnp_b   = (const float*)d_in[9];
  const float* W1      = (const float*)d_in[10];
  const float* bu1     = (const float*)d_in[11];
  const float* ba1     = (const float*)d_in[12];
  const float* bnc1_g  = (const float*)d_in[13];
  const float* bnc1_b  = (const float*)d_in[14];
  const float* W2      = (const float*)d_in[15];
  const float* bu2     = (const float*)d_in[16];
  const float* ba2     = (const float*)d_in[17];
  const float* bnc2_g  = (const float*)d_in[18];
  const float* bnc2_b  = (const float*)d_in[19];
  const float* Wfc     = (const float*)d_in[20];
  const float* bufc    = (const float*)d_in[21];
  const float* bafc    = (const float*)d_in[22];

  float* ws    = (float*)d_ws;
  float* out1  = ws;                          // 32*256*14*14 (NCHW)
  float* a1    = out1  + 32 * 256 * 14 * 14;  // [b][144][16]
  float* pose1 = a1    + 32 * 144 * 16;       // [b][144][256]
  float* a2    = pose1 + 32 * 144 * 256;      // [b][36][16]
  float* pose2 = a2    + 32 * 36 * 16;        // [b][36][256]
  float* a3    = pose2 + 32 * 36 * 256;       // [b][36][16]
  float* pose3 = a3    + 32 * 36 * 16;        // [b][36][256]
  float* a4    = pose3 + 32 * 36 * 256;       // [b][25][10]
  float* partial_p = a4 + 8000;               // NKC x [32][144][256]
  const size_t ksl_p = (size_t)32 * 144 * 256;
  const size_t ksl_a = (size_t)32 * 144 * 16;
  float* partial_a8 = partial_p + 8 * ksl_p;
  float* partial_a4 = partial_p + 4 * ksl_p;
  const size_t base_floats = 3493696;
  const size_t need8 = (base_floats + 8 * (ksl_p + ksl_a)) * 4;
  const size_t need4 = (base_floats + 4 * (ksl_p + ksl_a)) * 4;

  k_conv1<<<6272, 256, 0, stream>>>(x, conv1_w, bn1_g, bn1_b, out1);
  if (ws_size >= need8) {
    k_conv2_part4p<8><<<32 * 4 * 8, 192, 0, stream>>>(out1, convp_w, partial_p);
    k_conv2_part4a<8><<<32 * 8, 192, 0, stream>>>(out1, conva_w, partial_a8);
    k_conv2_red<8><<<1224, 256, 0, stream>>>(partial_p, partial_a8,
                                             bna_g, bna_b, bnp_g, bnp_b,
                                             a1, pose1);
  } else if (ws_size >= need4) {
    k_conv2_part4p<4><<<32 * 4 * 4, 192, 0, stream>>>(out1, convp_w, partial_p);
    k_conv2_part4a<4><<<32 * 4, 192, 0, stream>>>(out1, conva_w, partial_a4);
    k_conv2_red<4><<<1224, 256, 0, stream>>>(partial_p, partial_a4,
                                             bna_g, bna_b, bnp_g, bnp_b,
                                             a1, pose1);
  } else {
    k_conv2<<<288, 192, 0, stream>>>(out1, conva_w, convp_w, bna_g, bna_b,
                                     bnp_g, bnp_b, a1, pose1);
  }
  k_routing<3, 2, 1, 12, 12, 6, 6, 16><<<32 * 36, 512, 0, stream>>>(
      a1, pose1, W1, bu1, ba1, nullptr, nullptr, a2, pose2);
  k_routing<3, 1, 1, 6, 6, 6, 6, 16><<<32 * 36, 512, 0, stream>>>(
      a2, pose2, W2, bu2, ba2, bnc1_g, bnc1_b, a3, pose3);
  k_routing<4, 1, 1, 6, 6, 5, 5, 10><<<32 * 25, 512, 0, stream>>>(
      a3, pose3, Wfc, bufc, bafc, bnc2_g, bnc2_b, a4, nullptr);
  k_mean<<<5, 64, 0, stream>>>(a4, (float*)d_out);
}

// Round 20
// 383.985 us; speedup vs baseline: 1.0082x; 1.0082x over previous
//
#include <hip/hip_runtime.h>
#include <math.h>

#define EM_EPS 1e-8f
#define BN_SC 0.999995000037f   // 1/sqrt(1+1e-5)
#define LOG2PI 1.8378770664093453f

// ---------------- conv1 (5x5 s2 VALID) + bn1 ----------------
__global__ __launch_bounds__(256) void k_conv1(
    const float* __restrict__ x, const float* __restrict__ w,
    const float* __restrict__ g, const float* __restrict__ bb,
    float* __restrict__ out) {
  int idx = blockIdx.x * 256 + threadIdx.x;
  int ox = idx % 14; int t = idx / 14;
  int oy = t % 14; t /= 14;
  int co = t % 256; int b = t / 256;
  const float* xb = x + b * 3 * 1024;
  const float* wc = w + co * 75;
  float acc = 0.f;
  #pragma unroll
  for (int ci = 0; ci < 3; ++ci) {
    const float* xc = xb + ci * 1024 + (oy * 2) * 32 + ox * 2;
    const float* wk = wc + ci * 25;
    #pragma unroll
    for (int kh = 0; kh < 5; ++kh)
      #pragma unroll
      for (int kw = 0; kw < 5; ++kw)
        acc = fmaf(xc[kh * 32 + kw], wk[kh * 5 + kw], acc);
  }
  out[idx] = acc * (g[co] * BN_SC) + bb[co];
}

// ------------- conv2 partial, 4 co per thread; K-split; partial [kc][b][px][288] --
template<int NCI>
__global__ __launch_bounds__(192, 4) void k_conv2_part4(
    const float* __restrict__ in,
    const float* __restrict__ wa, const float* __restrict__ wp,
    float* __restrict__ partial) {
  constexpr int NKC = 256 / NCI;
  __shared__ float s_in[8 * 14 * 16];    // [ci8][iy][ix pad16]
  __shared__ float s_w[72 * 68];         // [ci8*9+tap][co pad68]

  const int t   = threadIdx.x;
  const int row = t >> 4;
  const int cg  = t & 15;
  const int b   = blockIdx.x / (5 * NKC);
  const int r   = blockIdx.x % (5 * NKC);
  const int gco = (r / NKC) * 64;
  const int kc  = r % NKC;
  const float* inb = in + (size_t)b * 50176;

  float acc[4][12];
  #pragma unroll
  for (int u = 0; u < 4; ++u)
    #pragma unroll
    for (int px = 0; px < 12; ++px) acc[u][px] = 0.f;

  for (int cc = 0; cc < NCI / 8; ++cc) {
    const int ci0 = kc * NCI + cc * 8;
    __syncthreads();
    for (int idx = t; idx < 1568; idx += 192) {
      int ci = idx / 196, rr = idx - ci * 196;
      int iy = rr / 14, ix = rr - iy * 14;
      s_in[ci * 224 + iy * 16 + ix] = inb[(size_t)ci0 * 196 + idx];
    }
    for (int idx = t; idx < 4608; idx += 192) {
      int co = idx / 72, rem = idx - co * 72;
      int c = gco + co;
      float val = 0.f;
      if (c < 16) val = wa[c * 2304 + ci0 * 9 + rem];
      else if (c < 272) val = wp[(c - 16) * 2304 + ci0 * 9 + rem];
      s_w[rem * 68 + co] = val;
    }
    __syncthreads();

    for (int ci = 0; ci < 8; ++ci) {
      float rin[3][16];
      #pragma unroll
      for (int kh = 0; kh < 3; ++kh) {
        const float4* rp = (const float4*)&s_in[ci * 224 + (row + kh) * 16];
        #pragma unroll
        for (int x = 0; x < 4; ++x)
          *(float4*)&rin[kh][x * 4] = rp[x];
      }
      #pragma unroll
      for (int kh = 0; kh < 3; ++kh) {
        #pragma unroll
        for (int kw = 0; kw < 3; ++kw) {
          const float4 wq = *(const float4*)&s_w[(ci * 9 + kh * 3 + kw) * 68 + cg * 4];
          #pragma unroll
          for (int px = 0; px < 12; ++px) {
            float iv = rin[kh][px + kw];
            acc[0][px] = fmaf(iv, wq.x, acc[0][px]);
            acc[1][px] = fmaf(iv, wq.y, acc[1][px]);
            acc[2][px] = fmaf(iv, wq.z, acc[2][px]);
            acc[3][px] = fmaf(iv, wq.w, acc[3][px]);
          }
        }
      }
    }
  }

  const int c = gco + cg * 4;
  if (c < 288) {
    #pragma unroll
    for (int px = 0; px < 12; ++px) {
      float* dst = partial +
          (((size_t)(kc * 32 + b) * 144) + row * 12 + px) * 288 + c;
      *(float4*)dst = make_float4(acc[0][px], acc[1][px], acc[2][px], acc[3][px]);
    }
  }
}

// ------------- conv2 reduce (vectorized quads): sum NKC partials + bn -------
template<int NKC>
__global__ __launch_bounds__(256) void k_conv2_red(
    const float* __restrict__ partial,
    const float* __restrict__ ga, const float* __restrict__ bba,
    const float* __restrict__ gp, const float* __restrict__ bbp,
    float* __restrict__ a1, float* __restrict__ pose1) {
  int q = blockIdx.x * 256 + threadIdx.x;
  if (q >= 32 * 144 * 68) return;
  int cq = q % 68; int r = q / 68;
  int px = r % 144; int b = r / 144;
  const int c4 = cq * 4;
  const size_t base = ((size_t)b * 144 + px) * 288 + c4;
  const size_t kstr = (size_t)32 * 144 * 288;
  float4 s = make_float4(0.f, 0.f, 0.f, 0.f);
  #pragma unroll
  for (int k = 0; k < NKC; ++k) {
    float4 v = *(const float4*)(partial + base + k * kstr);
    s.x += v.x; s.y += v.y; s.z += v.z; s.w += v.w;
  }
  if (c4 < 16) {
    float4 o;
    o.x = 1.f / (1.f + __expf(-(s.x * (ga[c4 + 0] * BN_SC) + bba[c4 + 0])));
    o.y = 1.f / (1.f + __expf(-(s.y * (ga[c4 + 1] * BN_SC) + bba[c4 + 1])));
    o.z = 1.f / (1.f + __expf(-(s.z * (ga[c4 + 2] * BN_SC) + bba[c4 + 2])));
    o.w = 1.f / (1.f + __expf(-(s.w * (ga[c4 + 3] * BN_SC) + bba[c4 + 3])));
    *(float4*)(a1 + ((size_t)b * 144 + px) * 16 + c4) = o;
  } else {
    const int cp = c4 - 16;
    float4 o;
    o.x = s.x * (gp[cp + 0] * BN_SC) + bbp[cp + 0];
    o.y = s.y * (gp[cp + 1] * BN_SC) + bbp[cp + 1];
    o.z = s.z * (gp[cp + 2] * BN_SC) + bbp[cp + 2];
    o.w = s.w * (gp[cp + 3] * BN_SC) + bbp[cp + 3];
    *(float4*)(pose1 + ((size_t)b * 144 + px) * 256 + cp) = o;
  }
}

// ------------- conv2 single-pass fallback (ws too small); channel-last out ----
__global__ __launch_bounds__(192) void k_conv2(
    const float* __restrict__ in,
    const float* __restrict__ wa, const float* __restrict__ wp,
    const float* __restrict__ ga, const float* __restrict__ bba,
    const float* __restrict__ gp, const float* __restrict__ bbp,
    float* __restrict__ a1, float* __restrict__ pose1) {
  __shared__ float s_in[16 * 14 * 16];
  __shared__ float s_w[16 * 9 * 34];

  const int t   = threadIdx.x;
  const int row = t >> 4;
  const int cg  = t & 15;
  const int b   = blockIdx.x / 9;
  const int gco = (blockIdx.x % 9) * 32;
  const float* inb = in + b * 50176;

  float acc[2][12];
  #pragma unroll
  for (int u = 0; u < 2; ++u)
    #pragma unroll
    for (int px = 0; px < 12; ++px) acc[u][px] = 0.f;

  for (int ch = 0; ch < 16; ++ch) {
    __syncthreads();
    for (int idx = t; idx < 3136; idx += 192) {
      int ci = idx / 196, rr = idx - ci * 196;
      int iy = rr / 14, ix = rr - iy * 14;
      s_in[ci * 224 + iy * 16 + ix] = inb[ch * 3136 + idx];
    }
    for (int idx = t; idx < 4608; idx += 192) {
      int co = idx / 144, rem = idx - co * 144;
      int c = gco + co;
      float val = 0.f;
      if (c < 272) {
        const float* wrow = (c < 16) ? (wa + c * 2304) : (wp + (c - 16) * 2304);
        val = wrow[ch * 144 + rem];
      }
      s_w[rem * 34 + co] = val;
    }
    __syncthreads();

    for (int ci = 0; ci < 16; ++ci) {
      float rin[3][16];
      #pragma unroll
      for (int kh = 0; kh < 3; ++kh) {
        const float4* rp = (const float4*)&s_in[ci * 224 + (row + kh) * 16];
        #pragma unroll
        for (int x = 0; x < 4; ++x)
          *(float4*)&rin[kh][x * 4] = rp[x];
      }
      #pragma unroll
      for (int kh = 0; kh < 3; ++kh) {
        #pragma unroll
        for (int kw = 0; kw < 3; ++kw) {
          float2 wv = *(const float2*)&s_w[(ci * 9 + kh * 3 + kw) * 34 + cg * 2];
          #pragma unroll
          for (int px = 0; px < 12; ++px) {
            float iv = rin[kh][px + kw];
            acc[0][px] = fmaf(iv, wv.x, acc[0][px]);
            acc[1][px] = fmaf(iv, wv.y, acc[1][px]);
          }
        }
      }
    }
  }

  #pragma unroll
  for (int u = 0; u < 2; ++u) {
    int c = gco + cg * 2 + u;
    if (c >= 272) continue;
    if (c < 16) {
      float g_ = ga[c] * BN_SC, b_ = bba[c];
      #pragma unroll
      for (int px = 0; px < 12; ++px) {
        float v = acc[u][px] * g_ + b_;
        a1[((size_t)b * 144 + row * 12 + px) * 16 + c] = 1.f / (1.f + expf(-v));
      }
    } else {
      int cp = c - 16;
      float g_ = gp[cp] * BN_SC, b_ = bbp[cp];
      #pragma unroll
      for (int px = 0; px < 12; ++px)
        pose1[((size_t)b * 144 + row * 12 + px) * 256 + cp] = acc[u][px] * g_ + b_;
    }
  }
}

// ---------------- EM routing v9: channel-last I/O, 8 waves, 8 p's per lane ----
template<int K, int S, int P, int HIN, int WIN, int OH, int OW, int B>
__global__ __launch_bounds__(512, 1) void k_routing(
    const float* __restrict__ ag,
    const float* __restrict__ poseg,
    const float* __restrict__ Wg,      // (KKA,B,4,4)
    const float* __restrict__ bu, const float* __restrict__ ba,
    const float* __restrict__ bng, const float* __restrict__ bnb,
    float* __restrict__ aout_g,
    float* __restrict__ pose_out_g) {
  constexpr int KK = K * K;
  constexpr int KKA = KK * 16;
  constexpr int NW = 8;
  constexpr int KPW = KKA / NW;       // 18 or 32
  constexpr int NSTEP = KPW / 2;      // 9 or 16
  static_assert(KPW % 2 == 0, "KPW%2");

  __shared__ __attribute__((aligned(16))) float s_pp[KKA * 16];
  __shared__ float s_ain[KKA];
  __shared__ __attribute__((aligned(16))) float s_part[NW][2][16][20]; // U1[8]|U2[8]|RS
  __shared__ __attribute__((aligned(16))) float s_mu[16 * 20];   // [j][p] pad20
  __shared__ __attribute__((aligned(16))) float s_i2s[16 * 20];  // [j][p] pad20
  __shared__ float s_lt[16 * 16];    // [p][j] log(sigma2)
  __shared__ float s_rs[16];         // fRS per j
  __shared__ float s_Ej[16];

  const int t  = threadIdx.x;
  const int wv = t >> 6;
  const int ln = t & 63;
  const int j  = ln & 15;
  const int ph = (ln >> 4) & 1;
  const int kq = ln >> 5;
  const int jc = (j < B) ? j : 0;

  const int bi = blockIdx.x;
  const int b  = bi / (OH * OW);
  const int l  = bi % (OH * OW);
  const int oy = l / OW, ox = l % OW;

  // ---- coalesced staging: per tap, contiguous 256 (pose) / 16 (a) floats ----
  for (int idx = t; idx < KK * 256; idx += 512) {
    int kki = idx >> 8, c = idx & 255;
    int kh = kki / K, kw = kki % K;
    int iy = oy * S - P + kh, ix = ox * S - P + kw;
    float val = 0.f;
    if (iy >= 0 && iy < HIN && ix >= 0 && ix < WIN) {
      val = poseg[((size_t)((b * HIN + iy) * WIN + ix)) * 256 + c];
      if (bng) val = val * (bng[c] * BN_SC) + bnb[c];
    }
    s_pp[idx] = val;
  }
  for (int idx = t; idx < KK * 16; idx += 512) {
    int kki = idx >> 4, acap = idx & 15;
    int kh = kki / K, kw = kki % K;
    int iy = oy * S - P + kh, ix = ox * S - P + kw;
    float val = 0.f;
    if (iy >= 0 && iy < HIN && ix >= 0 && ix < WIN)
      val = ag[((size_t)((b * HIN + iy) * WIN + ix)) * 16 + acap];
    s_ain[idx] = val;
  }
  __syncthreads();

  const int kbase = wv * KPW + kq;
  const float* wjc = Wg + (size_t)jc * 16;

  float p95 = 0.95f;
  for (int it = 0; it < 3; ++it) {
    const float lam = 0.01f * (1.0f - p95);
    p95 *= 0.95f;
    float U1[8], U2[8], RS = 0.f;
    #pragma unroll
    for (int p = 0; p < 8; ++p) { U1[p] = 0.f; U2[p] = 0.f; }

    float mu[8], i2s[8], Ej = 0.f;
    if (it > 0) {
      const float4* mp = (const float4*)&s_mu[j * 20 + ph * 8];
      const float4* ip = (const float4*)&s_i2s[j * 20 + ph * 8];
      float4 m0 = mp[0], m1 = mp[1], i0 = ip[0], i1 = ip[1];
      mu[0] = m0.x; mu[1] = m0.y; mu[2] = m0.z; mu[3] = m0.w;
      mu[4] = m1.x; mu[5] = m1.y; mu[6] = m1.z; mu[7] = m1.w;
      i2s[0] = i0.x; i2s[1] = i0.y; i2s[2] = i0.z; i2s[3] = i0.w;
      i2s[4] = i1.x; i2s[5] = i1.y; i2s[6] = i1.z; i2s[7] = i1.w;
      Ej = s_Ej[j];
    }

    for (int st = 0; st < NSTEP; ++st) {
      const int k = kbase + st * 2;
      const float4* wrp = (const float4*)(wjc + (size_t)k * B * 16);
      const float4 cw0 = wrp[0], cw1 = wrp[1], cw2 = wrp[2], cw3 = wrp[3];
      const float4* pr = (const float4*)&s_pp[k * 16 + ph * 8];
      const float4 pA = pr[0], pB = pr[1];
      const float ain = s_ain[k];
      float vv[8];
      vv[0] = pA.x * cw0.x + pA.y * cw1.x + pA.z * cw2.x + pA.w * cw3.x;
      vv[1] = pA.x * cw0.y + pA.y * cw1.y + pA.z * cw2.y + pA.w * cw3.y;
      vv[2] = pA.x * cw0.z + pA.y * cw1.z + pA.z * cw2.z + pA.w * cw3.z;
      vv[3] = pA.x * cw0.w + pA.y * cw1.w + pA.z * cw2.w + pA.w * cw3.w;
      vv[4] = pB.x * cw0.x + pB.y * cw1.x + pB.z * cw2.x + pB.w * cw3.x;
      vv[5] = pB.x * cw0.y + pB.y * cw1.y + pB.z * cw2.y + pB.w * cw3.y;
      vv[6] = pB.x * cw0.z + pB.y * cw1.z + pB.z * cw2.z + pB.w * cw3.z;
      vv[7] = pB.x * cw0.w + pB.y * cw1.w + pB.z * cw2.w + pB.w * cw3.w;
      float ra;
      if (it == 0) {
        ra = ain * (1.0f / (float)B);
      } else {
        float sa = 0.f, sb = 0.f;
        #pragma unroll
        for (int z = 0; z < 4; ++z) {
          float d0 = vv[z] - mu[z];
          float d1 = vv[4 + z] - mu[4 + z];
          sa = fmaf(d0 * i2s[z], d0, sa);
          sb = fmaf(d1 * i2s[4 + z], d1, sb);
        }
        float ss = sa + sb;
        ss += __shfl_xor(ss, 16);
        float e = Ej * __expf(-ss);
        float sm = e + __shfl_xor(e, 1);
        sm += __shfl_xor(sm, 2);
        sm += __shfl_xor(sm, 4);
        sm += __shfl_xor(sm, 8);
        ra = e * __builtin_amdgcn_rcpf(sm + 1e-30f) * ain;
      }
      RS += ra;
      #pragma unroll
      for (int p = 0; p < 8; ++p) {
        float tv = ra * vv[p];
        U1[p] += tv;
        U2[p] = fmaf(tv, vv[p], U2[p]);
      }
    }

    #pragma unroll
    for (int p = 0; p < 8; ++p) {
      U1[p] += __shfl_xor(U1[p], 32);
      U2[p] += __shfl_xor(U2[p], 32);
    }
    RS += __shfl_xor(RS, 32);

    if (ln < 32) {
      float* dst = &s_part[wv][ph][j][0];
      ((float4*)dst)[0] = make_float4(U1[0], U1[1], U1[2], U1[3]);
      ((float4*)dst)[1] = make_float4(U1[4], U1[5], U1[6], U1[7]);
      ((float4*)dst)[2] = make_float4(U2[0], U2[1], U2[2], U2[3]);
      ((float4*)dst)[3] = make_float4(U2[4], U2[5], U2[6], U2[7]);
      dst[16] = RS;
    }
    __syncthreads();

    if (t < 256) {
      const int p2 = t >> 4;
      const int j2 = t & 15;
      const int ph2 = p2 >> 3, q = p2 & 7;
      float fU1 = 0.f, fU2 = 0.f, fRS = 0.f;
      #pragma unroll
      for (int w2 = 0; w2 < NW; ++w2) {
        fU1 += s_part[w2][ph2][j2][q];
        fU2 += s_part[w2][ph2][j2][8 + q];
        fRS += s_part[w2][ph2][j2][16];
      }
      const bool jv2 = (j2 < B);
      const float inv = 1.f / (fRS + EM_EPS);
      const float Cc  = fRS * inv;
      float muv = fU1 * inv;
      float s2 = fU2 * inv - muv * muv * (2.f - Cc);
      s2 = fmaxf(s2, 0.f) + EM_EPS;
      s_mu[j2 * 20 + p2]  = jv2 ? muv : 0.f;
      s_i2s[j2 * 20 + p2] = jv2 ? (0.5f * __builtin_amdgcn_rcpf(s2)) : 0.f;
      s_lt[p2 * 16 + j2]  = __logf(s2);
      if (p2 == 0) s_rs[j2] = fRS;
      if (it == 2 && jv2 && pose_out_g)
        pose_out_g[((size_t)((b * OH + oy) * OW + ox)) * 256 + j2 * 16 + p2] = muv;
    }
    __syncthreads();

    if (t < 16) {
      const int j2 = t;
      const bool jv2 = (j2 < B);
      float lsum = 0.f;
      #pragma unroll
      for (int p = 0; p < 16; ++p) lsum += s_lt[p * 16 + j2];
      const float fRS = s_rs[j2];
      const float cost = (16.f * bu[jv2 ? j2 : 0] + 0.5f * lsum) * fRS;
      const float aout = 1.f / (1.f + __expf(-(lam * (ba[jv2 ? j2 : 0] - cost))));
      if (it < 2) {
        const float L0 = -0.5f * (16.f * LOG2PI + lsum);
        const float lj = L0 + __logf(aout + EM_EPS);
        float mj = jv2 ? lj : -1e30f;
        mj = fmaxf(mj, __shfl_xor(mj, 1));
        mj = fmaxf(mj, __shfl_xor(mj, 2));
        mj = fmaxf(mj, __shfl_xor(mj, 4));
        mj = fmaxf(mj, __shfl_xor(mj, 8));
        s_Ej[j2] = jv2 ? __expf(lj - mj) : 0.f;
      } else if (jv2) {
        aout_g[((size_t)((b * OH + oy) * OW + ox)) * B + j2] = aout;
      }
    }
    if (it < 2) __syncthreads();
  }
}

// ---------------- spatial mean over a4 [b][25][10] ----------------
__global__ __launch_bounds__(64) void k_mean(const float* __restrict__ a4,
                                             float* __restrict__ out) {
  int idx = blockIdx.x * 64 + threadIdx.x;
  if (idx >= 320) return;
  int b = idx / 10, j = idx % 10;
  const float* pa = a4 + b * 250 + j;
  float s = 0.f;
  #pragma unroll
  for (int i = 0; i < 25; ++i) s += pa[i * 10];
  out[idx] = s * (1.f / 25.f);
}

extern "C" void kernel_launch(void* const* d_in, const int* in_sizes, int n_in,
                              void* d_out, int out_size, void* d_ws, size_t ws_size,
                              hipStream_t stream) {
  const float* x       = (const float*)d_in[0];
  const float* conv1_w = (const float*)d_in[1];
  const float* bn1_g   = (const float*)d_in[2];
  const float* bn1_b   = (const float*)d_in[3];
  const float* conva_w = (const float*)d_in[4];
  const float* bna_g   = (const float*)d_in[5];
  const float* bna_b   = (const float*)d_in[6];
  const float* convp_w = (const float*)d_in[7];
  const float* bnp_g   = (const float*)d_in[8];
  const float* bnp_b   = (const float*)d_in[9];
  const float* W1      = (const float*)d_in[10];
  const float* bu1     = (const float*)d_in[11];
  const float* ba1     = (const float*)d_in[12];
  const float* bnc1_g  = (const float*)d_in[13];
  const float* bnc1_b  = (const float*)d_in[14];
  const float* W2      = (const float*)d_in[15];
  const float* bu2     = (const float*)d_in[16];
  const float* ba2     = (const float*)d_in[17];
  const float* bnc2_g  = (const float*)d_in[18];
  const float* bnc2_b  = (const float*)d_in[19];
  const float* Wfc     = (const float*)d_in[20];
  const float* bufc    = (const float*)d_in[21];
  const float* bafc    = (const float*)d_in[22];

  float* ws    = (float*)d_ws;
  float* out1  = ws;                          // 32*256*14*14 (NCHW)
  float* a1    = out1  + 32 * 256 * 14 * 14;  // [b][144][16]
  float* pose1 = a1    + 32 * 144 * 16;       // [b][144][256]
  float* a2    = pose1 + 32 * 144 * 256;      // [b][36][16]
  float* pose2 = a2    + 32 * 36 * 16;        // [b][36][256]
  float* a3    = pose2 + 32 * 36 * 256;       // [b][36][16]
  float* pose3 = a3    + 32 * 36 * 16;        // [b][36][256]
  float* a4    = pose3 + 32 * 36 * 256;       // [b][25][10]
  float* partial = a4  + 8000;                // up to 8*[32][144][288]
  const size_t base_floats = 3493696;
  const size_t kslice = (size_t)32 * 144 * 288;
  const size_t need8 = (base_floats + 8 * kslice) * 4;
  const size_t need4 = (base_floats + 4 * kslice) * 4;

  k_conv1<<<6272, 256, 0, stream>>>(x, conv1_w, bn1_g, bn1_b, out1);
  if (ws_size >= need8) {
    k_conv2_part4<32><<<32 * 5 * 8, 192, 0, stream>>>(out1, conva_w, convp_w,
                                                      partial);
    k_conv2_red<8><<<(32 * 144 * 68 + 255) / 256, 256, 0, stream>>>(
        partial, bna_g, bna_b, bnp_g, bnp_b, a1, pose1);
  } else if (ws_size >= need4) {
    k_conv2_part4<64><<<32 * 5 * 4, 192, 0, stream>>>(out1, conva_w, convp_w,
                                                      partial);
    k_conv2_red<4><<<(32 * 144 * 68 + 255) / 256, 256, 0, stream>>>(
        partial, bna_g, bna_b, bnp_g, bnp_b, a1, pose1);
  } else {
    k_conv2<<<288, 192, 0, stream>>>(out1, conva_w, convp_w, bna_g, bna_b,
                                     bnp_g, bnp_b, a1, pose1);
  }
  k_routing<3, 2, 1, 12, 12, 6, 6, 16><<<32 * 36, 512, 0, stream>>>(
      a1, pose1, W1, bu1, ba1, nullptr, nullptr, a2, pose2);
  k_routing<3, 1, 1, 6, 6, 6, 6, 16><<<32 * 36, 512, 0, stream>>>(
      a2, pose2, W2, bu2, ba2, bnc1_g, bnc1_b, a3, pose3);
  k_routing<4, 1, 1, 6, 6, 5, 5, 10><<<32 * 25, 512, 0, stream>>>(
      a3, pose3, Wfc, bufc, bafc, bnc2_g, bnc2_b, a4, nullptr);
  k_mean<<<5, 64, 0, stream>>>(a4, (float*)d_out);
}